// Round 1
// 598.462 us; speedup vs baseline: 1.0514x; 1.0514x over previous
//
#include <hip/hip_runtime.h>
#include <cstdint>
#include <cstddef>

#define EPSC 1e-10f
typedef unsigned short u16;
typedef unsigned int u32;
typedef __attribute__((ext_vector_type(8))) short bf16x8;
typedef __attribute__((ext_vector_type(4))) float f32x4;

// ---- workspace layout ----
// bf16 element offsets (2B units)
#define XTX_B 0u          // (c,1024) layout, X, per level/b
#define XTY_B 7864320u    // (c,1024) layout, Y
#define XNX_B 15728640u   // (1024,c) layout, X
#define XNY_B 23592960u   // (1024,c) layout, Y
// float offsets (4B units); starts at byte 62914560
#define FB 15728640u
#define RNX_OFF (FB + 0u)        // 32 * 1024
#define RNY_OFF (FB + 32768u)
#define RMIN_OFF (FB + 65536u)   // 32 * 1024
#define CMIN_OFF (FB + 98304u)
#define MUX_OFF (FB + 131072u)   // 7680
#define MUY_OFF (FB + 138752u)
#define COVS_OFF (FB + 146432u)  // 32
#define ACC_OFF (FB + 146464u)

struct Tabs { int c[4], N[4], mo[4]; u32 off[4]; };
struct GArgs {
  const float* t[4];
  const float* g[4];
  const int* idx[4];
  int c[4], hw[4], N[4];
  u32 off[4];
};

__device__ __forceinline__ u16 f2bf(float f) {
  u32 u = __float_as_uint(f);
  u = (u + 0x7fffu + ((u >> 16) & 1u)) >> 16;
  return (u16)u;
}
__device__ __forceinline__ float bf2f(u16 h) { return __uint_as_float(((u32)h) << 16); }

// ---------------- K0: init mins/accumulators ----------------
__global__ void k_init(float* __restrict__ wsf) {
  int i = blockIdx.x * blockDim.x + threadIdx.x;
  if (i < 65536) ((unsigned*)(wsf + RMIN_OFF))[i] = 0x7f800000u; // RMIN+CMIN -> +inf
  if (i < 33) wsf[COVS_OFF + i] = 0.f;                           // COVS[32] + ACC
}

// ---------------- K1: fused gather (all 4 levels) -> bf16, two layouts ----------------
__global__ void k_gather_all(GArgs ga, u16* __restrict__ bfb) {
  // grid (16 n-tiles, 15 = sum(c/64) tiles, 16=which*8+b), block 256; 64ch x 64n tile
  __shared__ float Ls[64 * 67];
  int y = blockIdx.y;
  int L = (y >= 7) ? 3 : (y >= 3) ? 2 : (y >= 1) ? 1 : 0;
  int ybase = (L == 0) ? 0 : (L == 1) ? 1 : (L == 2) ? 3 : 7;
  int cb64 = y - ybase;
  int c = ga.c[L], hw = ga.hw[L], N = ga.N[L];
  const int* idx = ga.idx[L];
  int z = blockIdx.z, which = z >> 3, b = z & 7;
  int c0 = cb64 * 64, n0 = blockIdx.x * 64;
  int tid = threadIdx.x;
  const float* src = which ? ga.g[L] : ga.t[L];
  u16* dt = bfb + (which ? XTY_B : XTX_B) + ga.off[L] + (size_t)b * c * 1024;
  u16* dn = bfb + (which ? XNY_B : XNX_B) + ga.off[L] + (size_t)b * c * 1024;
  int nl = tid & 63, cb = tid >> 6;
  int n = n0 + nl;
  bool nv = n < N;
  int sp = nv ? (idx ? idx[b * N + n] : n) : 0;
  const float* sbase = src + ((size_t)b * c + c0) * hw;
#pragma unroll
  for (int r = 0; r < 16; ++r) {
    int ch = cb + r * 4;
    Ls[ch * 67 + nl] = nv ? sbase[(size_t)ch * hw + sp] : 0.f;
  }
  __syncthreads();
  // write (c,1024) layout: lanes along n, coalesced
#pragma unroll
  for (int r = 0; r < 16; ++r) {
    int ch = cb + r * 4;
    dt[(size_t)(c0 + ch) * 1024 + n] = f2bf(Ls[ch * 67 + nl]);
  }
  // write (1024,c) layout: lanes along ch, coalesced; LDS col read stride 67 -> conflict-free
#pragma unroll
  for (int r = 0; r < 16; ++r) {
    int nw = cb + r * 4;
    int chw = nl;
    dn[(size_t)(n0 + nw) * c + c0 + chw] = f2bf(Ls[chw * 67 + nw]);
  }
}

// ---------------- K2: reciprocal norms from (c,1024) bf16 ----------------
__global__ void k_rnorm(const u16* __restrict__ bfb, float* __restrict__ wsf, Tabs t) {
  int L = blockIdx.z;
  int c = t.c[L];
  int zy = blockIdx.y, which = zy >> 3, b = zy & 7;
  int n = blockIdx.x * 256 + threadIdx.x; // 0..1023
  const u16* P = bfb + (which ? XTY_B : XTX_B) + t.off[L] + (size_t)b * c * 1024;
  float s = 0.f;
  for (int ch = 0; ch < c; ch += 4) {
#pragma unroll
    for (int u = 0; u < 4; ++u) {
      float v = bf2f(P[(size_t)(ch + u) * 1024 + n]);
      s = fmaf(v, v, s);
    }
  }
  int z = L * 8 + b;
  wsf[(which ? RNY_OFF : RNX_OFF) + (size_t)z * 1024 + n] = 1.0f / (sqrtf(s) + EPSC);
}

// ---------------- K3: per-channel means from (c,1024) bf16 ----------------
__global__ void k_mu(const u16* __restrict__ bfb, float* __restrict__ wsf, Tabs t) {
  int L = blockIdx.z;
  int c = t.c[L], N = t.N[L];
  int zy = blockIdx.y, which = zy >> 3, b = zy & 7;
  int wv = threadIdx.x >> 6, lane = threadIdx.x & 63;
  int ch = blockIdx.x * 4 + wv;
  if (ch >= c) return;
  const u16* P = bfb + (which ? XTY_B : XTX_B) + t.off[L] + ((size_t)b * c + ch) * 1024;
  float s = 0.f;
  for (int n = lane; n < 1024; n += 64) s += bf2f(P[n]); // padded tail is zero
#pragma unroll
  for (int off = 32; off; off >>= 1) s += __shfl_down(s, off, 64);
  if (lane == 0) wsf[(which ? MUY_OFF : MUX_OFF) + t.mo[L] + (size_t)b * c + ch] = s * (1.0f / N);
}

// ---------------- K4: MFMA cosine-dist + fused row/col mins ----------------
__global__ __launch_bounds__(256) void k_cosmin(const u16* __restrict__ bfb, float* __restrict__ wsf, Tabs t) {
  // grid (8,8,32=L*8+b), block 256 = 4 waves (2x2); 128x128 D-tile; KT=64
  __shared__ __align__(16) u16 As[128 * 72];
  __shared__ __align__(16) u16 Bs[128 * 72];
  int z = blockIdx.z, L = z >> 3, b = z & 7;
  int c = t.c[L], N = t.N[L];
  const u16* X = bfb + XNX_B + t.off[L] + (size_t)b * c * 1024;
  const u16* Y = bfb + XNY_B + t.off[L] + (size_t)b * c * 1024;
  int i0 = blockIdx.x * 128, j0 = blockIdx.y * 128;
  int tid = threadIdx.x, lane = tid & 63, w = tid >> 6;
  int wi = w >> 1, wj = w & 1, q = lane >> 4, cl = lane & 15;
  f32x4 acc[4][4] = {};
  int srow = tid >> 3, sch = tid & 7;
  for (int k0 = 0; k0 < c; k0 += 64) {
#pragma unroll
    for (int rep = 0; rep < 4; ++rep) {
      int row = srow + rep * 32;
      uint4 va = *(const uint4*)(X + (size_t)(i0 + row) * c + k0 + sch * 8);
      uint4 vb = *(const uint4*)(Y + (size_t)(j0 + row) * c + k0 + sch * 8);
      *(uint4*)(As + row * 72 + sch * 8) = va;
      *(uint4*)(Bs + row * 72 + sch * 8) = vb;
    }
    __syncthreads();
#pragma unroll
    for (int h = 0; h < 2; ++h) {
      bf16x8 af[4], bq[4];
#pragma unroll
      for (int ti = 0; ti < 4; ++ti)
        af[ti] = *(const bf16x8*)(As + (wi * 64 + ti * 16 + cl) * 72 + h * 32 + q * 8);
#pragma unroll
      for (int tj = 0; tj < 4; ++tj)
        bq[tj] = *(const bf16x8*)(Bs + (wj * 64 + tj * 16 + cl) * 72 + h * 32 + q * 8);
#pragma unroll
      for (int ti = 0; ti < 4; ++ti)
#pragma unroll
        for (int tj = 0; tj < 4; ++tj)
          acc[ti][tj] = __builtin_amdgcn_mfma_f32_16x16x32_bf16(af[ti], bq[tj], acc[ti][tj], 0, 0, 0);
    }
    __syncthreads();
  }
  // epilogue: d = 1 - dot*rnx*rny ; C/D layout: col=lane&15, row=q*4+reg
  const float* rnx = wsf + RNX_OFF + (size_t)z * 1024;
  const float* rny = wsf + RNY_OFF + (size_t)z * 1024;
  unsigned* rminp = (unsigned*)(wsf + RMIN_OFF) + (size_t)z * 1024;
  unsigned* cminp = (unsigned*)(wsf + CMIN_OFF) + (size_t)z * 1024;
  const float INFV = __uint_as_float(0x7f800000u);
  int colg[4]; float rnyv[4]; float colmin[4];
#pragma unroll
  for (int tj = 0; tj < 4; ++tj) {
    colg[tj] = j0 + wj * 64 + tj * 16 + cl;
    rnyv[tj] = rny[colg[tj]];
    colmin[tj] = INFV;
  }
#pragma unroll
  for (int ti = 0; ti < 4; ++ti) {
#pragma unroll
    for (int r = 0; r < 4; ++r) {
      int rowg = i0 + wi * 64 + ti * 16 + q * 4 + r;
      float rx = rnx[rowg];
      bool rv = rowg < N;
      float rmin = INFV;
#pragma unroll
      for (int tj = 0; tj < 4; ++tj) {
        float d = 1.0f - acc[ti][tj][r] * rx * rnyv[tj];
        if (!rv || colg[tj] >= N) d = INFV;
        rmin = fminf(rmin, d);
        colmin[tj] = fminf(colmin[tj], d);
      }
      rmin = fminf(rmin, __shfl_xor(rmin, 1, 64));
      rmin = fminf(rmin, __shfl_xor(rmin, 2, 64));
      rmin = fminf(rmin, __shfl_xor(rmin, 4, 64));
      rmin = fminf(rmin, __shfl_xor(rmin, 8, 64));
      if (cl == 0 && rv) atomicMin(&rminp[rowg], __float_as_uint(rmin));
    }
  }
#pragma unroll
  for (int tj = 0; tj < 4; ++tj) {
    float cm = colmin[tj];
    cm = fminf(cm, __shfl_xor(cm, 16, 64));
    cm = fminf(cm, __shfl_xor(cm, 32, 64));
    if (q == 0 && colg[tj] < N) atomicMin(&cminp[colg[tj]], __float_as_uint(cm));
  }
}

// ---------------- K5 (v2): barrier-free wave-per-tile |covX-covY| ----------------
// One 32x32 upper-triangular tile of D = Gx - Gy per wave, fragments loaded
// directly from L2-resident (c,1024) bf16 buffers. Y's A-operand sign-flipped
// in-register so one MFMA chain accumulates Gx - Gy. 1480 waves = 370 blocks.
#define COVW_NBLK 370
__global__ __launch_bounds__(256) void k_covw(const u16* __restrict__ bfb, float* __restrict__ wsf, Tabs t) {
  // bijective XCD-chunk swizzle (m204): cluster consecutive tiles on one XCD
  int bid = blockIdx.x;
  int qx = COVW_NBLK >> 3, rx = COVW_NBLK & 7;      // 46, 2
  int xcd = bid & 7, pos = bid >> 3;
  int bsw = (xcd < rx ? xcd * (qx + 1) : rx * (qx + 1) + (xcd - rx) * qx) + pos;
  int w = bsw * 4 + (threadIdx.x >> 6);
  // decode wave -> (L, b, triangular tile); ordered L3-first (largest) for balance
  int L, b, tt, W;
  if (w < 1088)      { int r = w;        L = 3; b = r / 136; tt = r - b * 136; W = 16; }
  else if (w < 1376) { int r = w - 1088; L = 2; b = r / 36;  tt = r - b * 36;  W = 8; }
  else if (w < 1456) { int r = w - 1376; L = 1; b = r / 10;  tt = r - b * 10;  W = 4; }
  else               { int r = w - 1456; L = 0; b = r / 3;   tt = r - b * 3;   W = 2; }
  int ti = 0, rem = tt;
  while (rem >= W - ti) { rem -= (W - ti); ++ti; }   // wave-uniform, <=16 iters
  int tj = ti + rem;
  int c = t.c[L], N = t.N[L];
  const u16* Xp = bfb + XTX_B + t.off[L] + (size_t)b * c * 1024;
  const u16* Yp = bfb + XTY_B + t.off[L] + (size_t)b * c * 1024;
  int lane = threadIdx.x & 63, cl = lane & 15, qq = lane >> 4;
  int i0 = ti * 32, j0 = tj * 32;
  size_t aoff[2], boff[2];
#pragma unroll
  for (int u = 0; u < 2; ++u) {
    aoff[u] = (size_t)(i0 + u * 16 + cl) * 1024 + qq * 8;
    boff[u] = (size_t)(j0 + u * 16 + cl) * 1024 + qq * 8;
  }
  f32x4 acc[2][2] = {};
#pragma unroll 2
  for (int k0 = 0; k0 < 1024; k0 += 32) {
    bf16x8 ax[2], bx[2], ay[2], by[2];
#pragma unroll
    for (int u = 0; u < 2; ++u) {
      ax[u] = *(const bf16x8*)(Xp + aoff[u] + k0);
      bx[u] = *(const bf16x8*)(Xp + boff[u] + k0);
      ay[u] = *(const bf16x8*)(Yp + aoff[u] + k0);
      by[u] = *(const bf16x8*)(Yp + boff[u] + k0);
    }
#pragma unroll
    for (int u = 0; u < 2; ++u) {   // negate Y A-operand: exact bf16 sign flip
      uint4 t4 = *(uint4*)&ay[u];
      t4.x ^= 0x80008000u; t4.y ^= 0x80008000u; t4.z ^= 0x80008000u; t4.w ^= 0x80008000u;
      ay[u] = *(bf16x8*)&t4;
    }
#pragma unroll
    for (int u = 0; u < 2; ++u)
#pragma unroll
      for (int v = 0; v < 2; ++v) {
        acc[u][v] = __builtin_amdgcn_mfma_f32_16x16x32_bf16(ax[u], bx[v], acc[u][v], 0, 0, 0);
        acc[u][v] = __builtin_amdgcn_mfma_f32_16x16x32_bf16(ay[u], by[v], acc[u][v], 0, 0, 0);
      }
  }
  // epilogue: cx - cy = (D - N*(mxi*mxj - myi*myj)) / (N-1)
  const float* mux = wsf + MUX_OFF + t.mo[L] + (size_t)b * c;
  const float* muy = wsf + MUY_OFF + t.mo[L] + (size_t)b * c;
  float fN = (float)N, inv1 = 1.0f / (float)(N - 1);
  float mxj[2], myj[2];
#pragma unroll
  for (int v = 0; v < 2; ++v) {
    int jg = j0 + v * 16 + cl;
    mxj[v] = mux[jg]; myj[v] = muy[jg];
  }
  float s = 0.f;
#pragma unroll
  for (int u = 0; u < 2; ++u)
#pragma unroll
    for (int r = 0; r < 4; ++r) {
      int ig = i0 + u * 16 + qq * 4 + r;
      float mxi = mux[ig], myi = muy[ig];
#pragma unroll
      for (int v = 0; v < 2; ++v) {
        float d = (acc[u][v][r] - fN * (mxi * mxj[v] - myi * myj[v])) * inv1;
        s += fabsf(d);
      }
    }
  if (ti != tj) s += s;  // off-diagonal tile counted twice (symmetry)
#pragma unroll
  for (int o = 1; o < 64; o <<= 1) s += __shfl_xor(s, o, 64);
  if (lane == 0) atomicAdd(&wsf[COVS_OFF + (L * 8 + b)], s);
}

// ---------------- K6: per-(L,b) loss terms ----------------
__global__ void k_final(float* __restrict__ wsf, Tabs t) {
  __shared__ float red[4];
  int z = blockIdx.x, L = z >> 3, b = z & 7;
  int c = t.c[L], N = t.N[L];
  const unsigned* rmin = (const unsigned*)(wsf + RMIN_OFF) + (size_t)z * 1024;
  const unsigned* cmin = (const unsigned*)(wsf + CMIN_OFF) + (size_t)z * 1024;
  const float* mux = wsf + MUX_OFF + t.mo[L] + (size_t)b * c;
  const float* muy = wsf + MUY_OFF + t.mo[L] + (size_t)b * c;
  int tid = threadIdx.x;
  float sr = 0.f, sc = 0.f, sm = 0.f;
  for (int n = tid; n < N; n += 256) {
    sr += __uint_as_float(rmin[n]);
    sc += __uint_as_float(cmin[n]);
  }
  for (int ch = tid; ch < c; ch += 256) sm += fabsf(mux[ch] - muy[ch]);
  float vals[3] = {sr, sc, sm};
  float tot[3] = {0.f, 0.f, 0.f};
  for (int qq = 0; qq < 3; ++qq) {
    float v = vals[qq];
#pragma unroll
    for (int off = 32; off; off >>= 1) v += __shfl_down(v, off, 64);
    if ((tid & 63) == 0) red[tid >> 6] = v;
    __syncthreads();
    if (tid == 0) tot[qq] = red[0] + red[1] + red[2] + red[3];
    __syncthreads();
  }
  if (tid == 0) {
    float style = fmaxf(tot[0] / (float)N, tot[1] / (float)N);
    float mu_d = tot[2] / (float)c;
    float cov = wsf[COVS_OFF + z] / ((float)c * (float)c);
    atomicAdd(&wsf[ACC_OFF], style + mu_d + cov);
  }
}

__global__ void k_out(const float* __restrict__ wsf, float* __restrict__ out) {
  if (threadIdx.x == 0 && blockIdx.x == 0) out[0] = wsf[ACC_OFF] * 0.125f;
}

extern "C" void kernel_launch(void* const* d_in, const int* in_sizes, int n_in,
                              void* d_out, int out_size, void* d_ws, size_t ws_size,
                              hipStream_t stream) {
  (void)in_sizes; (void)n_in; (void)out_size; (void)ws_size;
  static const int LC[4] = {64, 128, 256, 512};
  static const int LN[4] = {1000, 1000, 1000, 1024};
  static const int LHW[4] = {65536, 16384, 4096, 1024};
  static const u32 LOFF[4] = {0u, 524288u, 1572864u, 3670016u}; // c*1024*8 cumulative
  static const int MO[4] = {0, 512, 1536, 3584};

  float* wsf = (float*)d_ws;
  u16* bfb = (u16*)d_ws;
  Tabs t;
  GArgs ga;
  for (int L = 0; L < 4; ++L) {
    t.c[L] = LC[L]; t.N[L] = LN[L]; t.mo[L] = MO[L]; t.off[L] = LOFF[L];
    ga.t[L] = (const float*)d_in[2 * L];
    ga.g[L] = (const float*)d_in[2 * L + 1];
    ga.idx[L] = (L < 3) ? (const int*)d_in[8 + L] : nullptr;
    ga.c[L] = LC[L]; ga.hw[L] = LHW[L]; ga.N[L] = LN[L]; ga.off[L] = LOFF[L];
  }

  k_init<<<dim3(256), dim3(256), 0, stream>>>(wsf);
  k_gather_all<<<dim3(16, 15, 16), dim3(256), 0, stream>>>(ga, bfb);
  k_rnorm<<<dim3(4, 16, 4), dim3(256), 0, stream>>>(bfb, wsf, t);
  k_mu<<<dim3(128, 16, 4), dim3(256), 0, stream>>>(bfb, wsf, t);
  k_cosmin<<<dim3(8, 8, 32), dim3(256), 0, stream>>>(bfb, wsf, t);
  k_covw<<<dim3(COVW_NBLK), dim3(256), 0, stream>>>(bfb, wsf, t);
  k_final<<<dim3(32), dim3(256), 0, stream>>>(wsf, t);
  k_out<<<dim3(1), dim3(64), 0, stream>>>(wsf, (float*)d_out);
}

// Round 2
// 575.390 us; speedup vs baseline: 1.0935x; 1.0401x over previous
//
#include <hip/hip_runtime.h>
#include <cstdint>
#include <cstddef>

#define EPSC 1e-10f
typedef unsigned short u16;
typedef unsigned int u32;
typedef __attribute__((ext_vector_type(8))) short bf16x8;
typedef __attribute__((ext_vector_type(4))) float f32x4;

// ---- workspace layout ----
// bf16 element offsets (2B units)
#define XTX_B 0u          // (c,1024) layout, X, per level/b
#define XTY_B 7864320u    // (c,1024) layout, Y
#define XNX_B 15728640u   // (1024,c) layout, X
#define XNY_B 23592960u   // (1024,c) layout, Y
// float offsets (4B units); starts at byte 62914560
#define FB 15728640u
#define RNX_OFF (FB + 0u)        // 32*1024 ssq sums (X)
#define RNY_OFF (FB + 32768u)
#define RMIN_OFF (FB + 65536u)   // 32 * 1024
#define CMIN_OFF (FB + 98304u)
#define MUX_OFF (FB + 131072u)   // 7680 channel sums (X)
#define MUY_OFF (FB + 138752u)
#define COVS_OFF (FB + 146432u)  // 32
#define ACC_OFF (FB + 146464u)

struct Tabs { int c[4], N[4], mo[4]; u32 off[4]; };
struct GArgs {
  const float* t[4];
  const float* g[4];
  const int* idx[4];
  int c[4], hw[4], N[4], mo[4];
  u32 off[4];
};

__device__ __forceinline__ u16 f2bf(float f) {
  u32 u = __float_as_uint(f);
  u = (u + 0x7fffu + ((u >> 16) & 1u)) >> 16;
  return (u16)u;
}
__device__ __forceinline__ float bf2f(u16 h) { return __uint_as_float(((u32)h) << 16); }

// ---------------- K0: init mins + zero accumulators ----------------
__global__ void k_init(float* __restrict__ wsf) {
  int i = blockIdx.x * blockDim.x + threadIdx.x;
  if (i < 65536) ((unsigned*)(wsf + RMIN_OFF))[i] = 0x7f800000u; // RMIN+CMIN -> +inf
  if (i < 65536) wsf[RNX_OFF + i] = 0.f;                         // RNX+RNY ssq accumulators
  if (i < 15393) wsf[MUX_OFF + i] = 0.f;                         // MUX+MUY+COVS+ACC
}

// ---------------- K1: fused gather -> bf16 two layouts + mu/ssq partials ----------------
__global__ void k_gather_all(GArgs ga, u16* __restrict__ bfb, float* __restrict__ wsf) {
  // grid (16 n-tiles, 15 = sum(c/64) tiles, 16=which*8+b), block 256; 64ch x 64n tile
  __shared__ float Ls[64 * 67];
  __shared__ float Rs[64];
  int y = blockIdx.y;
  int L = (y >= 7) ? 3 : (y >= 3) ? 2 : (y >= 1) ? 1 : 0;
  int ybase = (L == 0) ? 0 : (L == 1) ? 1 : (L == 2) ? 3 : 7;
  int cb64 = y - ybase;
  int c = ga.c[L], hw = ga.hw[L], N = ga.N[L];
  const int* idx = ga.idx[L];
  int z = blockIdx.z, which = z >> 3, b = z & 7;
  int c0 = cb64 * 64, n0 = blockIdx.x * 64;
  int tid = threadIdx.x;
  const float* src = which ? ga.g[L] : ga.t[L];
  u16* dt = bfb + (which ? XTY_B : XTX_B) + ga.off[L] + (size_t)b * c * 1024;
  u16* dn = bfb + (which ? XNY_B : XNX_B) + ga.off[L] + (size_t)b * c * 1024;
  float* musum = wsf + (which ? MUY_OFF : MUX_OFF) + ga.mo[L] + (size_t)b * c + c0;
  float* rnsum = wsf + (which ? RNY_OFF : RNX_OFF) + (size_t)(L * 8 + b) * 1024 + n0;
  int nl = tid & 63, cb = tid >> 6;
  int n = n0 + nl;
  bool nv = n < N;
  int sp = nv ? (idx ? idx[b * N + n] : n) : 0;
  const float* sbase = src + ((size_t)b * c + c0) * hw;
  float v[16];
#pragma unroll
  for (int r = 0; r < 16; ++r) {
    int ch = cb + r * 4;
    v[r] = nv ? sbase[(size_t)ch * hw + sp] : 0.f;
    Ls[ch * 67 + nl] = v[r];
  }
  if (tid < 64) Rs[tid] = 0.f;
  // per-thread ssq partial over this thread's 16 channels (fp32, pre-quantization)
  float s2 = 0.f;
#pragma unroll
  for (int r = 0; r < 16; ++r) s2 = fmaf(v[r], v[r], s2);
  // per-channel sum partials: wave cb holds all 64 n-values of ch = cb + 4r
#pragma unroll
  for (int r = 0; r < 16; ++r) {
    float s = v[r];
#pragma unroll
    for (int off = 32; off; off >>= 1) s += __shfl_down(s, off, 64);
    if (nl == 0) atomicAdd(&musum[cb + r * 4], s);
  }
  __syncthreads();
  atomicAdd(&Rs[nl], s2);
  // write (c,1024) layout: lanes along n, coalesced
#pragma unroll
  for (int r = 0; r < 16; ++r) {
    int ch = cb + r * 4;
    dt[(size_t)(c0 + ch) * 1024 + n] = f2bf(Ls[ch * 67 + nl]);
  }
  // write (1024,c) layout: lanes along ch, coalesced; LDS col read stride 67 -> conflict-free
#pragma unroll
  for (int r = 0; r < 16; ++r) {
    int nw = cb + r * 4;
    int chw = nl;
    dn[(size_t)(n0 + nw) * c + c0 + chw] = f2bf(Ls[chw * 67 + nw]);
  }
  __syncthreads();
  if (tid < 64) atomicAdd(&rnsum[tid], Rs[tid]);
}

// ---------------- K4 (v2): barrier-free MFMA cosine-dist + fused row/col mins ----------------
// Operands per z are <=2MB -> L2/L3-resident; load fragments directly, no LDS, no barriers.
__global__ __launch_bounds__(256) void k_cosmin(const u16* __restrict__ bfb, float* __restrict__ wsf, Tabs t) {
  // grid (8,8,32=L*8+b), block 256 = 4 waves (2x2); 128x128 D-tile per block
  int z = blockIdx.z, L = z >> 3, b = z & 7;
  int c = t.c[L], N = t.N[L];
  const u16* X = bfb + XNX_B + t.off[L] + (size_t)b * c * 1024;
  const u16* Y = bfb + XNY_B + t.off[L] + (size_t)b * c * 1024;
  int i0 = blockIdx.x * 128, j0 = blockIdx.y * 128;
  int tid = threadIdx.x, lane = tid & 63, w = tid >> 6;
  int wi = w >> 1, wj = w & 1, q = lane >> 4, cl = lane & 15;
  // fragment base pointers: lanes (cl, q=0..3) of one frag jointly cover a full 64B line
  const u16* ap[4];
  const u16* bp[4];
#pragma unroll
  for (int u = 0; u < 4; ++u) {
    ap[u] = X + (size_t)(i0 + wi * 64 + u * 16 + cl) * c + q * 8;
    bp[u] = Y + (size_t)(j0 + wj * 64 + u * 16 + cl) * c + q * 8;
  }
  f32x4 acc[4][4] = {};
  for (int k0 = 0; k0 < c; k0 += 32) {
    bf16x8 af[4], bq4[4];
#pragma unroll
    for (int u = 0; u < 4; ++u) af[u] = *(const bf16x8*)(ap[u] + k0);
#pragma unroll
    for (int u = 0; u < 4; ++u) bq4[u] = *(const bf16x8*)(bp[u] + k0);
#pragma unroll
    for (int ti = 0; ti < 4; ++ti)
#pragma unroll
      for (int tj = 0; tj < 4; ++tj)
        acc[ti][tj] = __builtin_amdgcn_mfma_f32_16x16x32_bf16(af[ti], bq4[tj], acc[ti][tj], 0, 0, 0);
  }
  // epilogue: d = 1 - dot/(||x||+eps)/(||y||+eps); rn arrays hold ssq sums
  const float* rnx = wsf + RNX_OFF + (size_t)z * 1024;
  const float* rny = wsf + RNY_OFF + (size_t)z * 1024;
  unsigned* rminp = (unsigned*)(wsf + RMIN_OFF) + (size_t)z * 1024;
  unsigned* cminp = (unsigned*)(wsf + CMIN_OFF) + (size_t)z * 1024;
  const float INFV = __uint_as_float(0x7f800000u);
  int colg[4]; float rnyv[4]; float colmin[4];
#pragma unroll
  for (int tj = 0; tj < 4; ++tj) {
    colg[tj] = j0 + wj * 64 + tj * 16 + cl;
    rnyv[tj] = 1.0f / (sqrtf(rny[colg[tj]]) + EPSC);
    colmin[tj] = INFV;
  }
#pragma unroll
  for (int ti = 0; ti < 4; ++ti) {
#pragma unroll
    for (int r = 0; r < 4; ++r) {
      int rowg = i0 + wi * 64 + ti * 16 + q * 4 + r;
      float rx = 1.0f / (sqrtf(rnx[rowg]) + EPSC);
      bool rv = rowg < N;
      float rmin = INFV;
#pragma unroll
      for (int tj = 0; tj < 4; ++tj) {
        float d = 1.0f - acc[ti][tj][r] * rx * rnyv[tj];
        if (!rv || colg[tj] >= N) d = INFV;
        rmin = fminf(rmin, d);
        colmin[tj] = fminf(colmin[tj], d);
      }
      rmin = fminf(rmin, __shfl_xor(rmin, 1, 64));
      rmin = fminf(rmin, __shfl_xor(rmin, 2, 64));
      rmin = fminf(rmin, __shfl_xor(rmin, 4, 64));
      rmin = fminf(rmin, __shfl_xor(rmin, 8, 64));
      if (cl == 0 && rv) atomicMin(&rminp[rowg], __float_as_uint(rmin));
    }
  }
#pragma unroll
  for (int tj = 0; tj < 4; ++tj) {
    float cm = colmin[tj];
    cm = fminf(cm, __shfl_xor(cm, 16, 64));
    cm = fminf(cm, __shfl_xor(cm, 32, 64));
    if (q == 0 && colg[tj] < N) atomicMin(&cminp[colg[tj]], __float_as_uint(cm));
  }
}

// ---------------- K5: barrier-free wave-per-tile |covX-covY| ----------------
#define COVW_NBLK 370
__global__ __launch_bounds__(256) void k_covw(const u16* __restrict__ bfb, float* __restrict__ wsf, Tabs t) {
  // bijective XCD-chunk swizzle (m204)
  int bid = blockIdx.x;
  int qx = COVW_NBLK >> 3, rx = COVW_NBLK & 7;      // 46, 2
  int xcd = bid & 7, pos = bid >> 3;
  int bsw = (xcd < rx ? xcd * (qx + 1) : rx * (qx + 1) + (xcd - rx) * qx) + pos;
  int w = bsw * 4 + (threadIdx.x >> 6);
  // decode wave -> (L, b, triangular tile); largest level first
  int L, b, tt, W;
  if (w < 1088)      { int r = w;        L = 3; b = r / 136; tt = r - b * 136; W = 16; }
  else if (w < 1376) { int r = w - 1088; L = 2; b = r / 36;  tt = r - b * 36;  W = 8; }
  else if (w < 1456) { int r = w - 1376; L = 1; b = r / 10;  tt = r - b * 10;  W = 4; }
  else               { int r = w - 1456; L = 0; b = r / 3;   tt = r - b * 3;   W = 2; }
  int ti = 0, rem = tt;
  while (rem >= W - ti) { rem -= (W - ti); ++ti; }   // wave-uniform, <=16 iters
  int tj = ti + rem;
  int c = t.c[L], N = t.N[L];
  const u16* Xp = bfb + XTX_B + t.off[L] + (size_t)b * c * 1024;
  const u16* Yp = bfb + XTY_B + t.off[L] + (size_t)b * c * 1024;
  int lane = threadIdx.x & 63, cl = lane & 15, qq = lane >> 4;
  int i0 = ti * 32, j0 = tj * 32;
  size_t aoff[2], boff[2];
#pragma unroll
  for (int u = 0; u < 2; ++u) {
    aoff[u] = (size_t)(i0 + u * 16 + cl) * 1024 + qq * 8;
    boff[u] = (size_t)(j0 + u * 16 + cl) * 1024 + qq * 8;
  }
  f32x4 acc[2][2] = {};
#pragma unroll 2
  for (int k0 = 0; k0 < 1024; k0 += 32) {
    bf16x8 ax[2], bx[2], ay[2], by[2];
#pragma unroll
    for (int u = 0; u < 2; ++u) {
      ax[u] = *(const bf16x8*)(Xp + aoff[u] + k0);
      bx[u] = *(const bf16x8*)(Xp + boff[u] + k0);
      ay[u] = *(const bf16x8*)(Yp + aoff[u] + k0);
      by[u] = *(const bf16x8*)(Yp + boff[u] + k0);
    }
#pragma unroll
    for (int u = 0; u < 2; ++u) {   // negate Y A-operand: exact bf16 sign flip
      uint4 t4 = *(uint4*)&ay[u];
      t4.x ^= 0x80008000u; t4.y ^= 0x80008000u; t4.z ^= 0x80008000u; t4.w ^= 0x80008000u;
      ay[u] = *(bf16x8*)&t4;
    }
#pragma unroll
    for (int u = 0; u < 2; ++u)
#pragma unroll
      for (int v = 0; v < 2; ++v) {
        acc[u][v] = __builtin_amdgcn_mfma_f32_16x16x32_bf16(ax[u], bx[v], acc[u][v], 0, 0, 0);
        acc[u][v] = __builtin_amdgcn_mfma_f32_16x16x32_bf16(ay[u], by[v], acc[u][v], 0, 0, 0);
      }
  }
  // epilogue: cov diff with mu SUMS S: cx-cy = (D - (Sxi*Sxj - Syi*Syj)/N) / (N-1)
  const float* mux = wsf + MUX_OFF + t.mo[L] + (size_t)b * c;
  const float* muy = wsf + MUY_OFF + t.mo[L] + (size_t)b * c;
  float fN = (float)N, inv1 = 1.0f / (float)(N - 1), invN = 1.0f / fN;
  float mxj[2], myj[2];
#pragma unroll
  for (int v = 0; v < 2; ++v) {
    int jg = j0 + v * 16 + cl;
    mxj[v] = mux[jg]; myj[v] = muy[jg];
  }
  float s = 0.f;
#pragma unroll
  for (int u = 0; u < 2; ++u)
#pragma unroll
    for (int r = 0; r < 4; ++r) {
      int ig = i0 + u * 16 + qq * 4 + r;
      float mxi = mux[ig], myi = muy[ig];
#pragma unroll
      for (int v = 0; v < 2; ++v) {
        float d = (acc[u][v][r] - (mxi * mxj[v] - myi * myj[v]) * invN) * inv1;
        s += fabsf(d);
      }
    }
  if (ti != tj) s += s;  // off-diagonal tile counted twice (symmetry)
#pragma unroll
  for (int o = 1; o < 64; o <<= 1) s += __shfl_xor(s, o, 64);
  if (lane == 0) atomicAdd(&wsf[COVS_OFF + (L * 8 + b)], s);
}

// ---------------- K6: per-(L,b) loss terms ----------------
__global__ void k_final(float* __restrict__ wsf, Tabs t) {
  __shared__ float red[4];
  int z = blockIdx.x, L = z >> 3, b = z & 7;
  int c = t.c[L], N = t.N[L];
  const unsigned* rmin = (const unsigned*)(wsf + RMIN_OFF) + (size_t)z * 1024;
  const unsigned* cmin = (const unsigned*)(wsf + CMIN_OFF) + (size_t)z * 1024;
  const float* mux = wsf + MUX_OFF + t.mo[L] + (size_t)b * c;
  const float* muy = wsf + MUY_OFF + t.mo[L] + (size_t)b * c;
  int tid = threadIdx.x;
  float sr = 0.f, sc = 0.f, sm = 0.f;
  for (int n = tid; n < N; n += 256) {
    sr += __uint_as_float(rmin[n]);
    sc += __uint_as_float(cmin[n]);
  }
  for (int ch = tid; ch < c; ch += 256) sm += fabsf(mux[ch] - muy[ch]); // sums -> /N later
  float vals[3] = {sr, sc, sm};
  float tot[3] = {0.f, 0.f, 0.f};
  for (int qq = 0; qq < 3; ++qq) {
    float v = vals[qq];
#pragma unroll
    for (int off = 32; off; off >>= 1) v += __shfl_down(v, off, 64);
    if ((tid & 63) == 0) red[tid >> 6] = v;
    __syncthreads();
    if (tid == 0) tot[qq] = red[0] + red[1] + red[2] + red[3];
    __syncthreads();
  }
  if (tid == 0) {
    float style = fmaxf(tot[0] / (float)N, tot[1] / (float)N);
    float mu_d = tot[2] / ((float)N * (float)c);
    float cov = wsf[COVS_OFF + z] / ((float)c * (float)c);
    atomicAdd(&wsf[ACC_OFF], style + mu_d + cov);
  }
}

__global__ void k_out(const float* __restrict__ wsf, float* __restrict__ out) {
  if (threadIdx.x == 0 && blockIdx.x == 0) out[0] = wsf[ACC_OFF] * 0.125f;
}

extern "C" void kernel_launch(void* const* d_in, const int* in_sizes, int n_in,
                              void* d_out, int out_size, void* d_ws, size_t ws_size,
                              hipStream_t stream) {
  (void)in_sizes; (void)n_in; (void)out_size; (void)ws_size;
  static const int LC[4] = {64, 128, 256, 512};
  static const int LN[4] = {1000, 1000, 1000, 1024};
  static const int LHW[4] = {65536, 16384, 4096, 1024};
  static const u32 LOFF[4] = {0u, 524288u, 1572864u, 3670016u}; // c*1024*8 cumulative
  static const int MO[4] = {0, 512, 1536, 3584};

  float* wsf = (float*)d_ws;
  u16* bfb = (u16*)d_ws;
  Tabs t;
  GArgs ga;
  for (int L = 0; L < 4; ++L) {
    t.c[L] = LC[L]; t.N[L] = LN[L]; t.mo[L] = MO[L]; t.off[L] = LOFF[L];
    ga.t[L] = (const float*)d_in[2 * L];
    ga.g[L] = (const float*)d_in[2 * L + 1];
    ga.idx[L] = (L < 3) ? (const int*)d_in[8 + L] : nullptr;
    ga.c[L] = LC[L]; ga.hw[L] = LHW[L]; ga.N[L] = LN[L]; ga.mo[L] = MO[L]; ga.off[L] = LOFF[L];
  }

  k_init<<<dim3(256), dim3(256), 0, stream>>>(wsf);
  k_gather_all<<<dim3(16, 15, 16), dim3(256), 0, stream>>>(ga, bfb, wsf);
  k_cosmin<<<dim3(8, 8, 32), dim3(256), 0, stream>>>(bfb, wsf, t);
  k_covw<<<dim3(COVW_NBLK), dim3(256), 0, stream>>>(bfb, wsf, t);
  k_final<<<dim3(32), dim3(256), 0, stream>>>(wsf, t);
  k_out<<<dim3(1), dim3(64), 0, stream>>>(wsf, (float*)d_out);
}

// Round 3
// 564.654 us; speedup vs baseline: 1.1143x; 1.0190x over previous
//
#include <hip/hip_runtime.h>
#include <cstdint>
#include <cstddef>

#define EPSC 1e-10f
typedef unsigned short u16;
typedef unsigned int u32;
typedef __attribute__((ext_vector_type(8))) short bf16x8;
typedef __attribute__((ext_vector_type(4))) float f32x4;

// ---- workspace layout ----
// bf16 element offsets (2B units)
#define XTX_B 0u          // (c,1024) layout, X, per level/b
#define XTY_B 7864320u    // (c,1024) layout, Y
#define XNX_B 15728640u   // (1024,c) layout, X
#define XNY_B 23592960u   // (1024,c) layout, Y
// float offsets (4B units); starts at byte 62914560
#define FB 15728640u
#define RNX_OFF (FB + 0u)        // 32*1024 ssq sums (X)
#define RNY_OFF (FB + 32768u)
#define RMIN_OFF (FB + 65536u)   // 32 * 1024
#define CMIN_OFF (FB + 98304u)
#define MUX_OFF (FB + 131072u)   // 7680 channel sums (X)
#define MUY_OFF (FB + 138752u)
#define COVS_OFF (FB + 146432u)  // 32
#define ACC_OFF (FB + 146464u)
#define CNT_OFF (FB + 146465u)

struct Tabs { int c[4], N[4], mo[4]; u32 off[4]; };
struct GArgs {
  const float* t[4];
  const float* g[4];
  const int* idx[4];
  int c[4], hw[4], N[4], mo[4];
  u32 off[4];
};

__device__ __forceinline__ u16 f2bf(float f) {
  u32 u = __float_as_uint(f);
  u = (u + 0x7fffu + ((u >> 16) & 1u)) >> 16;
  return (u16)u;
}
__device__ __forceinline__ float bf2f(u16 h) { return __uint_as_float(((u32)h) << 16); }

typedef __attribute__((address_space(3))) unsigned lds_as_t;
typedef __attribute__((address_space(1))) const unsigned glb_as_t;
// direct-to-LDS gather load: per-lane global src, wave-uniform LDS base + lane*4.
// No result VGPR -> all 16 loads stay in flight on vmcnt regardless of regalloc.
__device__ __forceinline__ void gload_lds4(const float* g, float* l) {
  __builtin_amdgcn_global_load_lds((glb_as_t*)g, (lds_as_t*)l, 4, 0, 0);
}

// ---------------- K0: init mins + zero accumulators ----------------
__global__ void k_init(float* __restrict__ wsf) {
  int i = blockIdx.x * blockDim.x + threadIdx.x;
  if (i < 65536) ((unsigned*)(wsf + RMIN_OFF))[i] = 0x7f800000u; // RMIN+CMIN -> +inf
  if (i < 65536) wsf[RNX_OFF + i] = 0.f;                         // RNX+RNY ssq accumulators
  if (i < 15394) wsf[MUX_OFF + i] = 0.f;                         // MUX+MUY+COVS+ACC+CNT
}

// ---------------- K1: fused gather via global_load_lds + mu/ssq partials ----------------
__global__ void k_gather_all(GArgs ga, u16* __restrict__ bfb, float* __restrict__ wsf) {
  // grid (16 n-tiles, 15 = sum(c/64) tiles, 16=which*8+b), block 256; 64ch x 64n tile
  __shared__ float Ls[64 * 67];
  __shared__ float Rs[64];
  int y = blockIdx.y;
  int L = (y >= 7) ? 3 : (y >= 3) ? 2 : (y >= 1) ? 1 : 0;
  int ybase = (L == 0) ? 0 : (L == 1) ? 1 : (L == 2) ? 3 : 7;
  int cb64 = y - ybase;
  int c = ga.c[L], hw = ga.hw[L], N = ga.N[L];
  const int* idx = ga.idx[L];
  int z = blockIdx.z, which = z >> 3, b = z & 7;
  int c0 = cb64 * 64, n0 = blockIdx.x * 64;
  int tid = threadIdx.x;
  const float* src = which ? ga.g[L] : ga.t[L];
  u16* dt = bfb + (which ? XTY_B : XTX_B) + ga.off[L] + (size_t)b * c * 1024;
  u16* dn = bfb + (which ? XNY_B : XNX_B) + ga.off[L] + (size_t)b * c * 1024;
  float* musum = wsf + (which ? MUY_OFF : MUX_OFF) + ga.mo[L] + (size_t)b * c + c0;
  float* rnsum = wsf + (which ? RNY_OFF : RNX_OFF) + (size_t)(L * 8 + b) * 1024 + n0;
  int nl = tid & 63, cb = tid >> 6;
  int n = n0 + nl;
  bool nv = n < N;
  int sp = nv ? (idx ? idx[b * N + n] : n) : 0;
  const float* sbase = src + ((size_t)b * c + c0) * hw;
  if (tid < 64) Rs[tid] = 0.f;
  // 16 register-free direct-to-LDS gathers, all outstanding on vmcnt
#pragma unroll
  for (int r = 0; r < 16; ++r) {
    int ch = cb + r * 4;
    gload_lds4(sbase + (size_t)ch * hw + sp, &Ls[ch * 67]);
  }
  asm volatile("s_waitcnt vmcnt(0)" ::: "memory");
  __syncthreads();
  // pass A: (c,1024) layout writes + mu/ssq partials (invalid lanes -> 0)
  float s2 = 0.f;
#pragma unroll
  for (int r = 0; r < 16; ++r) {
    int ch = cb + r * 4;
    float val = nv ? Ls[ch * 67 + nl] : 0.f;
    dt[(size_t)(c0 + ch) * 1024 + n] = f2bf(val);
    s2 = fmaf(val, val, s2);
    float s = val;
#pragma unroll
    for (int off = 32; off; off >>= 1) s += __shfl_down(s, off, 64);
    if (nl == 0) atomicAdd(&musum[ch], s);
  }
  atomicAdd(&Rs[nl], s2);
  // pass B: (1024,c) layout writes; LDS col read stride 67 -> conflict-free
#pragma unroll
  for (int r = 0; r < 16; ++r) {
    int nw = cb + r * 4;
    int ng = n0 + nw;
    float val = (ng < N) ? Ls[nl * 67 + nw] : 0.f;
    dn[(size_t)ng * c + c0 + nl] = f2bf(val);
  }
  __syncthreads();
  if (tid < 64) atomicAdd(&rnsum[tid], Rs[tid]);
}

// ---------------- cosmin body: barrier-free MFMA cosine-dist + fused row/col mins ----------------
__device__ __forceinline__ void cosmin_body(const u16* __restrict__ bfb, float* __restrict__ wsf,
                                            const Tabs& t, int bx, int by, int z) {
  int L = z >> 3, b = z & 7;
  int c = t.c[L], N = t.N[L];
  const u16* X = bfb + XNX_B + t.off[L] + (size_t)b * c * 1024;
  const u16* Y = bfb + XNY_B + t.off[L] + (size_t)b * c * 1024;
  int i0 = bx * 128, j0 = by * 128;
  int tid = threadIdx.x, lane = tid & 63, w = tid >> 6;
  int wi = w >> 1, wj = w & 1, q = lane >> 4, cl = lane & 15;
  const u16* ap[4];
  const u16* bp[4];
#pragma unroll
  for (int u = 0; u < 4; ++u) {
    ap[u] = X + (size_t)(i0 + wi * 64 + u * 16 + cl) * c + q * 8;
    bp[u] = Y + (size_t)(j0 + wj * 64 + u * 16 + cl) * c + q * 8;
  }
  f32x4 acc[4][4] = {};
  for (int k0 = 0; k0 < c; k0 += 32) {
    bf16x8 af[4], bq4[4];
#pragma unroll
    for (int u = 0; u < 4; ++u) af[u] = *(const bf16x8*)(ap[u] + k0);
#pragma unroll
    for (int u = 0; u < 4; ++u) bq4[u] = *(const bf16x8*)(bp[u] + k0);
#pragma unroll
    for (int ti = 0; ti < 4; ++ti)
#pragma unroll
      for (int tj = 0; tj < 4; ++tj)
        acc[ti][tj] = __builtin_amdgcn_mfma_f32_16x16x32_bf16(af[ti], bq4[tj], acc[ti][tj], 0, 0, 0);
  }
  const float* rnx = wsf + RNX_OFF + (size_t)z * 1024;
  const float* rny = wsf + RNY_OFF + (size_t)z * 1024;
  unsigned* rminp = (unsigned*)(wsf + RMIN_OFF) + (size_t)z * 1024;
  unsigned* cminp = (unsigned*)(wsf + CMIN_OFF) + (size_t)z * 1024;
  const float INFV = __uint_as_float(0x7f800000u);
  int colg[4]; float rnyv[4]; float colmin[4];
#pragma unroll
  for (int tj = 0; tj < 4; ++tj) {
    colg[tj] = j0 + wj * 64 + tj * 16 + cl;
    rnyv[tj] = 1.0f / (sqrtf(rny[colg[tj]]) + EPSC);
    colmin[tj] = INFV;
  }
#pragma unroll
  for (int ti = 0; ti < 4; ++ti) {
#pragma unroll
    for (int r = 0; r < 4; ++r) {
      int rowg = i0 + wi * 64 + ti * 16 + q * 4 + r;
      float rx = 1.0f / (sqrtf(rnx[rowg]) + EPSC);
      bool rv = rowg < N;
      float rmin = INFV;
#pragma unroll
      for (int tj = 0; tj < 4; ++tj) {
        float d = 1.0f - acc[ti][tj][r] * rx * rnyv[tj];
        if (!rv || colg[tj] >= N) d = INFV;
        rmin = fminf(rmin, d);
        colmin[tj] = fminf(colmin[tj], d);
      }
      rmin = fminf(rmin, __shfl_xor(rmin, 1, 64));
      rmin = fminf(rmin, __shfl_xor(rmin, 2, 64));
      rmin = fminf(rmin, __shfl_xor(rmin, 4, 64));
      rmin = fminf(rmin, __shfl_xor(rmin, 8, 64));
      if (cl == 0 && rv) atomicMin(&rminp[rowg], __float_as_uint(rmin));
    }
  }
#pragma unroll
  for (int tj = 0; tj < 4; ++tj) {
    float cm = colmin[tj];
    cm = fminf(cm, __shfl_xor(cm, 16, 64));
    cm = fminf(cm, __shfl_xor(cm, 32, 64));
    if (q == 0 && colg[tj] < N) atomicMin(&cminp[colg[tj]], __float_as_uint(cm));
  }
}

// ---------------- covw body: barrier-free wave-per-tile |covX-covY| ----------------
#define COVW_NBLK 370
__device__ __forceinline__ void covw_body(const u16* __restrict__ bfb, float* __restrict__ wsf,
                                          const Tabs& t, int bid) {
  int qx = COVW_NBLK >> 3, rx = COVW_NBLK & 7;      // 46, 2
  int xcd = bid & 7, pos = bid >> 3;
  int bsw = (xcd < rx ? xcd * (qx + 1) : rx * (qx + 1) + (xcd - rx) * qx) + pos;
  int w = bsw * 4 + (threadIdx.x >> 6);
  int L, b, tt, W;
  if (w < 1088)      { int r = w;        L = 3; b = r / 136; tt = r - b * 136; W = 16; }
  else if (w < 1376) { int r = w - 1088; L = 2; b = r / 36;  tt = r - b * 36;  W = 8; }
  else if (w < 1456) { int r = w - 1376; L = 1; b = r / 10;  tt = r - b * 10;  W = 4; }
  else               { int r = w - 1456; L = 0; b = r / 3;   tt = r - b * 3;   W = 2; }
  int ti = 0, rem = tt;
  while (rem >= W - ti) { rem -= (W - ti); ++ti; }   // wave-uniform, <=16 iters
  int tj = ti + rem;
  int c = t.c[L], N = t.N[L];
  const u16* Xp = bfb + XTX_B + t.off[L] + (size_t)b * c * 1024;
  const u16* Yp = bfb + XTY_B + t.off[L] + (size_t)b * c * 1024;
  int lane = threadIdx.x & 63, cl = lane & 15, qq = lane >> 4;
  int i0 = ti * 32, j0 = tj * 32;
  size_t aoff[2], boff[2];
#pragma unroll
  for (int u = 0; u < 2; ++u) {
    aoff[u] = (size_t)(i0 + u * 16 + cl) * 1024 + qq * 8;
    boff[u] = (size_t)(j0 + u * 16 + cl) * 1024 + qq * 8;
  }
  f32x4 acc[2][2] = {};
#pragma unroll 2
  for (int k0 = 0; k0 < 1024; k0 += 32) {
    bf16x8 ax[2], bx[2], ay[2], by[2];
#pragma unroll
    for (int u = 0; u < 2; ++u) {
      ax[u] = *(const bf16x8*)(Xp + aoff[u] + k0);
      bx[u] = *(const bf16x8*)(Xp + boff[u] + k0);
      ay[u] = *(const bf16x8*)(Yp + aoff[u] + k0);
      by[u] = *(const bf16x8*)(Yp + boff[u] + k0);
    }
#pragma unroll
    for (int u = 0; u < 2; ++u) {   // negate Y A-operand: exact bf16 sign flip
      uint4 t4 = *(uint4*)&ay[u];
      t4.x ^= 0x80008000u; t4.y ^= 0x80008000u; t4.z ^= 0x80008000u; t4.w ^= 0x80008000u;
      ay[u] = *(bf16x8*)&t4;
    }
#pragma unroll
    for (int u = 0; u < 2; ++u)
#pragma unroll
      for (int v = 0; v < 2; ++v) {
        acc[u][v] = __builtin_amdgcn_mfma_f32_16x16x32_bf16(ax[u], bx[v], acc[u][v], 0, 0, 0);
        acc[u][v] = __builtin_amdgcn_mfma_f32_16x16x32_bf16(ay[u], by[v], acc[u][v], 0, 0, 0);
      }
  }
  const float* mux = wsf + MUX_OFF + t.mo[L] + (size_t)b * c;
  const float* muy = wsf + MUY_OFF + t.mo[L] + (size_t)b * c;
  float fN = (float)N, inv1 = 1.0f / (float)(N - 1), invN = 1.0f / fN;
  float mxj[2], myj[2];
#pragma unroll
  for (int v = 0; v < 2; ++v) {
    int jg = j0 + v * 16 + cl;
    mxj[v] = mux[jg]; myj[v] = muy[jg];
  }
  float s = 0.f;
#pragma unroll
  for (int u = 0; u < 2; ++u)
#pragma unroll
    for (int r = 0; r < 4; ++r) {
      int ig = i0 + u * 16 + qq * 4 + r;
      float mxi = mux[ig], myi = muy[ig];
#pragma unroll
      for (int v = 0; v < 2; ++v) {
        float d = (acc[u][v][r] - (mxi * mxj[v] - myi * myj[v]) * invN) * inv1;
        s += fabsf(d);
      }
    }
  if (ti != tj) s += s;  // off-diagonal tile counted twice (symmetry)
#pragma unroll
  for (int o = 1; o < 64; o <<= 1) s += __shfl_xor(s, o, 64);
  if (lane == 0) atomicAdd(&wsf[COVS_OFF + (L * 8 + b)], s);
}

// ---------------- K2: fused independent MFMA work (covw first, then cosmin) ----------------
#define FUSE_NBLK (COVW_NBLK + 2048)
__global__ __launch_bounds__(256) void k_mfma(const u16* __restrict__ bfb, float* __restrict__ wsf, Tabs t) {
  int bid = blockIdx.x;
  if (bid < COVW_NBLK) { covw_body(bfb, wsf, t, bid); return; }
  int cbid = bid - COVW_NBLK;
  int z = cbid >> 6, rest = cbid & 63;
  cosmin_body(bfb, wsf, t, rest >> 3, rest & 7, z);
}

// ---------------- K3: per-(L,b) loss terms + self-terminating output ----------------
__global__ void k_final(float* __restrict__ wsf, float* __restrict__ out, Tabs t) {
  __shared__ float red[4];
  int z = blockIdx.x, L = z >> 3, b = z & 7;
  int c = t.c[L], N = t.N[L];
  const unsigned* rmin = (const unsigned*)(wsf + RMIN_OFF) + (size_t)z * 1024;
  const unsigned* cmin = (const unsigned*)(wsf + CMIN_OFF) + (size_t)z * 1024;
  const float* mux = wsf + MUX_OFF + t.mo[L] + (size_t)b * c;
  const float* muy = wsf + MUY_OFF + t.mo[L] + (size_t)b * c;
  int tid = threadIdx.x;
  float sr = 0.f, sc = 0.f, sm = 0.f;
  for (int n = tid; n < N; n += 256) {
    sr += __uint_as_float(rmin[n]);
    sc += __uint_as_float(cmin[n]);
  }
  for (int ch = tid; ch < c; ch += 256) sm += fabsf(mux[ch] - muy[ch]); // sums -> /N later
  float vals[3] = {sr, sc, sm};
  float tot[3] = {0.f, 0.f, 0.f};
  for (int qq = 0; qq < 3; ++qq) {
    float v = vals[qq];
#pragma unroll
    for (int off = 32; off; off >>= 1) v += __shfl_down(v, off, 64);
    if ((tid & 63) == 0) red[tid >> 6] = v;
    __syncthreads();
    if (tid == 0) tot[qq] = red[0] + red[1] + red[2] + red[3];
    __syncthreads();
  }
  if (tid == 0) {
    float style = fmaxf(tot[0] / (float)N, tot[1] / (float)N);
    float mu_d = tot[2] / ((float)N * (float)c);
    float cov = wsf[COVS_OFF + z] / ((float)c * (float)c);
    atomicAdd(&wsf[ACC_OFF], style + mu_d + cov);
    __threadfence();
    unsigned old = atomicAdd((unsigned*)&wsf[CNT_OFF], 1u);
    if (old == 31u) {
      float acc = atomicAdd(&wsf[ACC_OFF], 0.0f); // atomic RMW read: device-coherent
      out[0] = acc * 0.125f;
    }
  }
}

extern "C" void kernel_launch(void* const* d_in, const int* in_sizes, int n_in,
                              void* d_out, int out_size, void* d_ws, size_t ws_size,
                              hipStream_t stream) {
  (void)in_sizes; (void)n_in; (void)out_size; (void)ws_size;
  static const int LC[4] = {64, 128, 256, 512};
  static const int LN[4] = {1000, 1000, 1000, 1024};
  static const int LHW[4] = {65536, 16384, 4096, 1024};
  static const u32 LOFF[4] = {0u, 524288u, 1572864u, 3670016u}; // c*1024*8 cumulative
  static const int MO[4] = {0, 512, 1536, 3584};

  float* wsf = (float*)d_ws;
  u16* bfb = (u16*)d_ws;
  Tabs t;
  GArgs ga;
  for (int L = 0; L < 4; ++L) {
    t.c[L] = LC[L]; t.N[L] = LN[L]; t.mo[L] = MO[L]; t.off[L] = LOFF[L];
    ga.t[L] = (const float*)d_in[2 * L];
    ga.g[L] = (const float*)d_in[2 * L + 1];
    ga.idx[L] = (L < 3) ? (const int*)d_in[8 + L] : nullptr;
    ga.c[L] = LC[L]; ga.hw[L] = LHW[L]; ga.N[L] = LN[L]; ga.mo[L] = MO[L]; ga.off[L] = LOFF[L];
  }

  k_init<<<dim3(256), dim3(256), 0, stream>>>(wsf);
  k_gather_all<<<dim3(16, 15, 16), dim3(256), 0, stream>>>(ga, bfb, wsf);
  k_mfma<<<dim3(FUSE_NBLK), dim3(256), 0, stream>>>(bfb, wsf, t);
  k_final<<<dim3(32), dim3(256), 0, stream>>>(wsf, (float*)d_out, t);
}